// Round 6
// baseline (242.655 us; speedup 1.0000x reference)
//
#include <hip/hip_runtime.h>
#include <hip/hip_bf16.h>
#include <cmath>

#define N_TOTAL 4096
#define HALF_N  2048
#define D_DIM   512

// ws layout (bytes):
//   [0,      16384) float sq[4096]        (row squared norms)
//   [16384,  20480) float colsum[1024]    (src cols 0..511, tgt cols 512..1023)  [zeroed]
//   [20480,  20496) double sumsq[2]       (sum of sq over src / tgt)             [zeroed]
//   [20496,  20520) double acc[3]         (xx, yy, xy kernel sums)               [zeroed]
//   [20520,  20532) float bw[3]           (bw_xx, bw_yy, bw_xy)

// ---------------- Kernel 1: row norms, column sums, sum-of-norms ----------------
__global__ __launch_bounds__(256) void k_rowstats(const float* __restrict__ x,
                                                  float* __restrict__ sq,
                                                  float* __restrict__ colsum,
                                                  double* __restrict__ sumsq) {
    __shared__ float cs[512];
    const int tid = threadIdx.x;
    cs[tid] = 0.f; cs[tid + 256] = 0.f;
    __syncthreads();

    const int w = tid >> 6, l = tid & 63;
    const int rb = blockIdx.x * 16;

    float colacc[8] = {0.f,0.f,0.f,0.f,0.f,0.f,0.f,0.f};
    double mysq = 0.0;

    #pragma unroll
    for (int r4 = 0; r4 < 4; ++r4) {
        const int row = rb + w + 4 * r4;
        const float4* p = (const float4*)(x + (size_t)row * D_DIM);
        float4 v0 = p[2 * l];
        float4 v1 = p[2 * l + 1];
        colacc[0] += v0.x; colacc[1] += v0.y; colacc[2] += v0.z; colacc[3] += v0.w;
        colacc[4] += v1.x; colacc[5] += v1.y; colacc[6] += v1.z; colacc[7] += v1.w;
        float s = v0.x*v0.x + v0.y*v0.y + v0.z*v0.z + v0.w*v0.w
                + v1.x*v1.x + v1.y*v1.y + v1.z*v1.z + v1.w*v1.w;
        #pragma unroll
        for (int off = 32; off; off >>= 1) s += __shfl_xor(s, off);
        if (l == 0) { sq[row] = s; mysq += (double)s; }
    }

    const int half = (rb < HALF_N) ? 0 : 1;
    if (l == 0) atomicAdd(&sumsq[half], mysq);

    #pragma unroll
    for (int k2 = 0; k2 < 8; ++k2) atomicAdd(&cs[8 * l + k2], colacc[k2]);
    __syncthreads();

    float* dst = colsum + half * 512;
    atomicAdd(&dst[tid],       cs[tid]);
    atomicAdd(&dst[tid + 256], cs[tid + 256]);
}

// ---------------- Kernel 2: bandwidths from analytic sums ----------------
__global__ __launch_bounds__(256) void k_bw(const float* __restrict__ colsum,
                                            const double* __restrict__ sumsq,
                                            float* __restrict__ bw) {
    const int tid = threadIdx.x;
    double pss = 0, ptt = 0, pst = 0;
    for (int c = tid; c < 512; c += 256) {
        double a = colsum[c], b = colsum[512 + c];
        pss += a * a; ptt += b * b; pst += a * b;
    }
    #pragma unroll
    for (int off = 32; off; off >>= 1) {
        pss += __shfl_xor(pss, off);
        ptt += __shfl_xor(ptt, off);
        pst += __shfl_xor(pst, off);
    }
    __shared__ double red[4][3];
    const int w = tid >> 6, l = tid & 63;
    if (l == 0) { red[w][0] = pss; red[w][1] = ptt; red[w][2] = pst; }
    __syncthreads();
    if (tid == 0) {
        double ss = red[0][0] + red[1][0] + red[2][0] + red[3][0];
        double tt = red[0][1] + red[1][1] + red[2][1] + red[3][1];
        double st = red[0][2] + red[1][2] + red[2][2] + red[3][2];
        const double n = (double)HALF_N;
        double Sss = 2.0 * n * sumsq[0] - 2.0 * ss;
        double Stt = 2.0 * n * sumsq[1] - 2.0 * tt;
        double Sst = n * (sumsq[0] + sumsq[1]) - 2.0 * st;
        const double denom = (double)N_TOTAL * (double)N_TOTAL - (double)N_TOTAL;
        // xx: sum over dup matrix = 4*Sss; /denom then /kernel_mul^2(=4)  -> Sss/denom
        bw[0] = (float)(Sss / denom);
        bw[1] = (float)(Stt / denom);
        bw[2] = (float)((Sss + Stt + 2.0 * Sst) / denom * 0.25);
    }
}

// ---------------- Kernel 3: triangular tiled gram + fused kernel-sum epilogue ----------------
#define BM 128
#define BK 32
#define LDT 132   // transposed-tile row stride (floats); 132%4==0 keeps float4 reads 16B-aligned
#define NTILE 32  // 4096/128
#define NWORK 528 // NTILE*(NTILE+1)/2 upper-tri tiles, launched FLAT for load balance

__global__ __launch_bounds__(256) void k_main(const float* __restrict__ x,
                                              const float* __restrict__ sq,
                                              const float* __restrict__ bw,
                                              double* __restrict__ acc) {
    // Decode flat index -> (bi,bj) upper triangle (row-major, incl. diagonal).
    // Row bi starts at o(bi) = 32*bi - bi*(bi-1)/2. Closed-form root + fixup.
    const int t = blockIdx.x;
    int bi = (int)((65.0f - sqrtf((float)(4225 - 8 * t))) * 0.5f);
    if (bi < 0) bi = 0;
    if (bi > NTILE - 1) bi = NTILE - 1;
    // fixup (<=2 iterations; wave-uniform)
    while (bi > 0 && (32 * bi - bi * (bi - 1) / 2) > t) --bi;
    while (bi < NTILE - 1 && (32 * (bi + 1) - (bi + 1) * bi / 2) <= t) ++bi;
    const int bj = bi + (t - (32 * bi - bi * (bi - 1) / 2));

    __shared__ float As[BK][LDT];
    __shared__ float Bs[BK][LDT];

    const int tid = threadIdx.x;
    const int tx = tid & 15, ty = tid >> 4;
    const int i0 = bi * BM, j0 = bj * BM;

    // Fragment layout (bank-conflict-free): each thread owns rows
    //   {4*ty..4*ty+3, 64+4*ty..64+4*ty+3} and cols {4*tx.., 64+4*tx..}.
    // Lane stride is 4 floats (16 B) -> B-reads 2-way (free), A-reads broadcast.
    float c[8][8];
    #pragma unroll
    for (int i = 0; i < 8; ++i)
        #pragma unroll
        for (int j = 0; j < 8; ++j) c[i][j] = 0.f;

    for (int k0 = 0; k0 < D_DIM; k0 += BK) {
        #pragma unroll
        for (int u = 0; u < 4; ++u) {
            const int f = tid + 256 * u;   // 0..1023 float4 slots (128 rows x 8 quads)
            const int row = f >> 3;
            const int q = f & 7;
            float4 va = *(const float4*)(x + (size_t)(i0 + row) * D_DIM + k0 + 4 * q);
            float4 vb = *(const float4*)(x + (size_t)(j0 + row) * D_DIM + k0 + 4 * q);
            As[4*q+0][row] = va.x; As[4*q+1][row] = va.y; As[4*q+2][row] = va.z; As[4*q+3][row] = va.w;
            Bs[4*q+0][row] = vb.x; Bs[4*q+1][row] = vb.y; Bs[4*q+2][row] = vb.z; Bs[4*q+3][row] = vb.w;
        }
        __syncthreads();

        #pragma unroll 4
        for (int kk = 0; kk < BK; ++kk) {
            float4 a0 = *(const float4*)&As[kk][4 * ty];
            float4 a1 = *(const float4*)&As[kk][4 * ty + 64];
            float4 b0 = *(const float4*)&Bs[kk][4 * tx];
            float4 b1 = *(const float4*)&Bs[kk][4 * tx + 64];
            const float a[8] = {a0.x,a0.y,a0.z,a0.w,a1.x,a1.y,a1.z,a1.w};
            const float b[8] = {b0.x,b0.y,b0.z,b0.w,b1.x,b1.y,b1.z,b1.w};
            #pragma unroll
            for (int i = 0; i < 8; ++i)
                #pragma unroll
                for (int j = 0; j < 8; ++j)
                    c[i][j] = fmaf(a[i], b[j], c[i][j]);
        }
        __syncthreads();
    }

    // epilogue: d2 = sq_i + sq_j - 2*G; accumulate 5-term gaussian kernel sums
    const bool iS = (i0 < HALF_N), jS = (j0 < HALF_N);
    const bool diagRegion = (iS == jS);          // block-uniform
    const double wgt = (bi == bj) ? 1.0 : 2.0;
    const float L2E = 1.4426950408889634f;
    const float cxy = -L2E / bw[2];
    const float cdg = diagRegion ? (-L2E / (iS ? bw[0] : bw[1])) : 0.f;

    float sqi[8], sqj[8];
    #pragma unroll
    for (int a = 0; a < 4; ++a) {
        sqi[a]     = sq[i0 + 4 * ty + a];
        sqi[a + 4] = sq[i0 + 64 + 4 * ty + a];
        sqj[a]     = sq[j0 + 4 * tx + a];
        sqj[a + 4] = sq[j0 + 64 + 4 * tx + a];
    }

    float sxy = 0.f, sdg = 0.f;
    #pragma unroll
    for (int i = 0; i < 8; ++i) {
        #pragma unroll
        for (int j = 0; j < 8; ++j) {
            const float d2 = sqi[i] + sqj[j] - 2.f * c[i][j];
            {
                const float tt = d2 * cxy;
                sxy += exp2f(tt) + exp2f(tt * 0.5f) + exp2f(tt * 0.25f)
                     + exp2f(tt * 0.125f) + exp2f(tt * 0.0625f);
            }
            if (diagRegion) {
                const float tt = d2 * cdg;
                sdg += exp2f(tt) + exp2f(tt * 0.5f) + exp2f(tt * 0.25f)
                     + exp2f(tt * 0.125f) + exp2f(tt * 0.0625f);
            }
        }
    }

    #pragma unroll
    for (int off = 32; off; off >>= 1) {
        sxy += __shfl_xor(sxy, off);
        sdg += __shfl_xor(sdg, off);
    }
    __shared__ float redA[4], redB[4];
    if ((tid & 63) == 0) { redA[tid >> 6] = sxy; redB[tid >> 6] = sdg; }
    __syncthreads();
    if (tid == 0) {
        double txy = (double)redA[0] + redA[1] + redA[2] + redA[3];
        atomicAdd(&acc[2], wgt * txy);
        if (diagRegion) {
            double tdg = (double)redB[0] + redB[1] + redB[2] + redB[3];
            atomicAdd(&acc[iS ? 0 : 1], wgt * tdg);
        }
    }
}

// ---------------- Kernel 4: finalize ----------------
__global__ void k_final(const double* __restrict__ acc, float* __restrict__ out) {
    const double hh = (double)HALF_N * (double)HALF_N;
    const double ff = (double)N_TOTAL * (double)N_TOTAL;
    double xx = acc[0] / hh;
    double yy = acc[1] / hh;
    double xy = acc[2] / ff;
    out[0] = (float)(xx + yy - 2.0 * xy);
}

extern "C" void kernel_launch(void* const* d_in, const int* in_sizes, int n_in,
                              void* d_out, int out_size, void* d_ws, size_t ws_size,
                              hipStream_t stream) {
    const float* latent = (const float*)d_in[0];
    // d_in[1] (domain) is unused: reference splits by position (fixed halves).

    char* wsb = (char*)d_ws;
    float*  sq     = (float*)wsb;                   // 4096 floats
    float*  colsum = (float*)(wsb + 16384);         // 1024 floats
    double* sumsq  = (double*)(wsb + 20480);        // 2 doubles
    double* acc    = (double*)(wsb + 20496);        // 3 doubles
    float*  bw     = (float*)(wsb + 20520);         // 3 floats

    // zero the accumulated region (ws is poisoned 0xAA before every launch)
    (void)hipMemsetAsync(wsb + 16384, 0, 20532 - 16384, stream);

    k_rowstats<<<256, 256, 0, stream>>>(latent, sq, colsum, sumsq);
    k_bw<<<1, 256, 0, stream>>>(colsum, sumsq, bw);
    k_main<<<NWORK, 256, 0, stream>>>(latent, sq, bw, acc);
    k_final<<<1, 1, 0, stream>>>(acc, (float*)d_out);
}